// Round 9
// baseline (64.960 us; speedup 1.0000x reference)
//
#include <hip/hip_runtime.h>
#include <math.h>

#define BB 16
#define NN 96
#define HH 256
#define NBIN 11
#define NBPAD 12   // bin row padded to 12 floats -> 48 B, 16-B aligned rows

// ---------------------------------------------------------------------------
// DPP wave64 sum -> wave-uniform scalar. Pure VALU, no LDS-unit traffic.
// ---------------------------------------------------------------------------
template <int CTRL>
__device__ __forceinline__ float dpp_add(float x) {
    int t = __builtin_amdgcn_update_dpp(0, __float_as_int(x),
                                        CTRL, 0xf, 0xf, true);
    return x + __int_as_float(t);
}

__device__ __forceinline__ float wave64_sum_uniform(float x) {
    x = dpp_add<0x111>(x);  // row_shr:1
    x = dpp_add<0x112>(x);  // row_shr:2
    x = dpp_add<0x114>(x);  // row_shr:4
    x = dpp_add<0x118>(x);  // row_shr:8
    x = dpp_add<0x142>(x);  // row_bcast:15
    x = dpp_add<0x143>(x);  // row_bcast:31
    return __int_as_float(__builtin_amdgcn_readlane(__float_as_int(x), 63));
}

// ---------------------------------------------------------------------------
// Kernel 1: proj[r][k] = sum_h inputs[r][h] * W_atom[h][k] + 0.5*b_bin[k]
// ---------------------------------------------------------------------------
#define ROWS_PER_BLOCK 4

__global__ __launch_bounds__(HH) void proj_kernel(
    const float* __restrict__ inputs,
    const float* __restrict__ W_atom,
    const float* __restrict__ b_bin,
    float* __restrict__ proj)
{
    __shared__ float rows[ROWS_PER_BLOCK][HH];
    const int r0 = blockIdx.x * ROWS_PER_BLOCK;
    const int k  = threadIdx.x;

    #pragma unroll
    for (int r = 0; r < ROWS_PER_BLOCK; ++r)
        rows[r][k] = inputs[(size_t)(r0 + r) * HH + k];
    __syncthreads();

    float acc[ROWS_PER_BLOCK];
    #pragma unroll
    for (int r = 0; r < ROWS_PER_BLOCK; ++r) acc[r] = 0.f;

    #pragma unroll 8
    for (int h = 0; h < HH; ++h) {
        const float w = W_atom[(size_t)h * HH + k];   // coalesced over k
        #pragma unroll
        for (int r = 0; r < ROWS_PER_BLOCK; ++r)
            acc[r] = fmaf(rows[r][h], w, acc[r]);     // LDS broadcast read
    }

    const float halfb = 0.5f * b_bin[k];
    #pragma unroll
    for (int r = 0; r < ROWS_PER_BLOCK; ++r)
        proj[(size_t)(r0 + r) * HH + k] = acc[r] + halfb;
}

// ---------------------------------------------------------------------------
// Kernel 2 (fused pair + score + context), 1-deep software pipeline:
//   step t+1's 8 global loads are issued BEFORE step t's compute so the
//   ~300-600 cyc L2/LLC latency hides under the ~600 cyc compute body.
//   Fully unrolled t-loop keeps double-buffer indices static (no scratch).
// ---------------------------------------------------------------------------
struct Step { float4 inj[4]; float4 prj[4]; };

__device__ __forceinline__ void load_step(const float* inb, const float* prb,
                                          int j0, Step& s) {
    #pragma unroll
    for (int u = 0; u < 4; ++u) {
        s.inj[u] = *(const float4*)(inb + (size_t)(j0 + 4 * u) * HH);
        s.prj[u] = *(const float4*)(prb + (size_t)(j0 + 4 * u) * HH);
    }
}

__global__ __launch_bounds__(256) void pair_ctx_kernel(
    const float* __restrict__ inputs,
    const float* __restrict__ bin_features,
    const float* __restrict__ W_bin,
    const float* __restrict__ w_score,
    const float* __restrict__ b_score,
    const float* __restrict__ proj,
    float* __restrict__ atom_pair,
    float* __restrict__ context)
{
    const int bi   = blockIdx.x;           // b*N + i
    const int b    = bi / NN;
    const int lane = threadIdx.x & 63;
    const int wave = threadIdx.x >> 6;     // 0..3
    const int k4   = lane << 2;            // float4 offset into H

    __shared__ float binf[NN * NBPAD];     // padded rows, 16-B aligned
    __shared__ float partial[3][HH];

    {
        const float* bp = bin_features + (size_t)bi * NN * NBIN;
        for (int t = threadIdx.x; t < NN * NBIN; t += 256)
            binf[(t / NBIN) * NBPAD + (t % NBIN)] = bp[t];
    }

    const float4 in_i = *(const float4*)(inputs + (size_t)bi * HH + k4);
    const float4 pr_i = *(const float4*)(proj   + (size_t)bi * HH + k4);
    const float4 ws   = *(const float4*)(w_score + k4);
    const float  bsc  = b_score[0];

    float4 wb[NBIN];
    #pragma unroll
    for (int c = 0; c < NBIN; ++c)
        wb[c] = *(const float4*)(W_bin + c * HH + k4);

    const float* inb = inputs + (size_t)b * NN * HH + k4;
    const float* prb = proj   + (size_t)b * NN * HH + k4;
    float*       apb = atom_pair + (size_t)bi * NN * HH + k4;

    __syncthreads();                       // binf ready

    float4 acc = make_float4(0.f, 0.f, 0.f, 0.f);

    Step sA, sB;
    load_step(inb, prb, wave, sA);         // prologue: step 0 in flight

    // 96 = 4 waves * 4 unroll * 6 steps; fully unrolled, A/B double-buffer
    #pragma unroll
    for (int t = 0; t < 6; ++t) {
        const Step& cur = (t & 1) ? sB : sA;
        Step&       nxt = (t & 1) ? sA : sB;
        const int j0 = wave + 16 * t;

        if (t < 5)                          // issue next step's loads FIRST
            load_step(inb, prb, j0 + 16, nxt);

        // ---- compute current step (loads for it already landed) ----
        #pragma unroll
        for (int u = 0; u < 4; ++u) {
            float4 ap;
            ap.x = in_i.x + cur.inj[u].x;  ap.y = in_i.y + cur.inj[u].y;
            ap.z = in_i.z + cur.inj[u].z;  ap.w = in_i.w + cur.inj[u].w;
            *(float4*)(apb + (size_t)(j0 + 4 * u) * HH) = ap;
        }

        float part[4];
        #pragma unroll
        for (int u = 0; u < 4; ++u) {
            const float4* bf4 = (const float4*)&binf[(j0 + 4 * u) * NBPAD];
            const float4 bq0 = bf4[0];
            const float4 bq1 = bf4[1];
            const float4 bq2 = bf4[2];
            const float bc[NBIN] = { bq0.x, bq0.y, bq0.z, bq0.w,
                                     bq1.x, bq1.y, bq1.z, bq1.w,
                                     bq2.x, bq2.y, bq2.z };

            float4 v;
            v.x = pr_i.x + cur.prj[u].x;  v.y = pr_i.y + cur.prj[u].y;
            v.z = pr_i.z + cur.prj[u].z;  v.w = pr_i.w + cur.prj[u].w;
            #pragma unroll
            for (int c = 0; c < NBIN; ++c) {
                v.x = fmaf(bc[c], wb[c].x, v.x);
                v.y = fmaf(bc[c], wb[c].y, v.y);
                v.z = fmaf(bc[c], wb[c].z, v.z);
                v.w = fmaf(bc[c], wb[c].w, v.w);
            }
            v.x = fmaxf(v.x, 0.f); v.y = fmaxf(v.y, 0.f);
            v.z = fmaxf(v.z, 0.f); v.w = fmaxf(v.w, 0.f);
            part[u] = v.x * ws.x + v.y * ws.y + v.z * ws.z + v.w * ws.w;
        }

        float s[4];
        #pragma unroll
        for (int u = 0; u < 4; ++u) {
            const float tot = wave64_sum_uniform(part[u]);
            s[u] = 1.f / (1.f + __expf(-(tot + bsc)));
        }

        #pragma unroll
        for (int u = 0; u < 4; ++u) {
            acc.x = fmaf(s[u], cur.inj[u].x, acc.x);
            acc.y = fmaf(s[u], cur.inj[u].y, acc.y);
            acc.z = fmaf(s[u], cur.inj[u].z, acc.z);
            acc.w = fmaf(s[u], cur.inj[u].w, acc.w);
        }
    }

    // cross-wave reduce of context accumulator
    if (wave > 0) *(float4*)(&partial[wave - 1][k4]) = acc;
    __syncthreads();
    if (wave == 0) {
        #pragma unroll
        for (int w = 0; w < 3; ++w) {
            const float4 pw = *(const float4*)(&partial[w][k4]);
            acc.x += pw.x; acc.y += pw.y; acc.z += pw.z; acc.w += pw.w;
        }
        *(float4*)(context + (size_t)bi * HH + k4) = acc;
    }
}

extern "C" void kernel_launch(void* const* d_in, const int* in_sizes, int n_in,
                              void* d_out, int out_size, void* d_ws, size_t ws_size,
                              hipStream_t stream)
{
    const float* inputs       = (const float*)d_in[0];   // (B,N,H)
    const float* bin_features = (const float*)d_in[1];   // (B,N,N,BIN)
    const float* W_atom       = (const float*)d_in[2];   // (H,H)
    const float* W_bin        = (const float*)d_in[3];   // (BIN,H)
    const float* b_bin        = (const float*)d_in[4];   // (H,)
    const float* w_score      = (const float*)d_in[5];   // (H,1)
    const float* b_score      = (const float*)d_in[6];   // (1,)

    float* context   = (float*)d_out;                         // B*N*H
    float* atom_pair = (float*)d_out + (size_t)BB * NN * HH;  // B*N*N*H

    float* proj = (float*)d_ws;                               // B*N*H floats

    proj_kernel<<<(BB * NN) / ROWS_PER_BLOCK, HH, 0, stream>>>(
        inputs, W_atom, b_bin, proj);

    pair_ctx_kernel<<<BB * NN, 256, 0, stream>>>(
        inputs, bin_features, W_bin, w_score, b_score, proj,
        atom_pair, context);
}